// Round 8
// baseline (340.079 us; speedup 1.0000x reference)
//
#include <hip/hip_runtime.h>
#include <stdint.h>

// Net_49177375539428: recursive tree-NN scorer, all-fp32.
//   k_base : base GEMV + d_score (round-2 verbatim) + zeroing of the
//            per-(graph,level) barrier flags used by k_treeX.
//   k_treeX: MULTI-CU level-synchronous tree sweep (round-7, validated:
//            79us) + NEXT-LEVEL W PREFETCH: each wave knows its level-(d-1)
//            node (same q=k+8w mapping); after finishing level-d work
//            (idle waves: immediately) it touches all 512 cache lines of
//            that node's 64KB W (8 loads/lane, 1 float per 128B line,
//            kept live via empty asm). The loads complete during other
//            waves' GEMVs + the ~2us cross-block barrier, so next level's
//            GEMV hits LLC/L2 instead of HBM (~900cy -> ~300-500cy per
//            ping-pong group, the per-level critical path).
//   k_step0: one block per edge-type e (round-2 verbatim).
//   k_steps: path chain, 16 e-rows per block (round-2 verbatim).

#define NND 128
#define DD  128
#define GG  8
#define VD  300
#define EDGEN 128
#define CH2 16         // e-rows per k_steps block
#define KSP 8          // blocks per graph in k_treeX

typedef unsigned int u32;

#define F_POS  (1<<16)
#define F_PATH (1<<17)
#define SKIPF  (F_POS|F_PATH)

// ---------------- K1: base embeddings + d_score + flag zero ----------------
__global__ void __launch_bounds__(128) k_base(
        const int* __restrict__ data, const int* __restrict__ posArr,
        const float* __restrict__ vecs, const float* __restrict__ dw,
        const float* __restrict__ db,   const float* __restrict__ sdw,
        const float* __restrict__ sb,
        float* __restrict__ base, float* __restrict__ dscore,
        int* __restrict__ flagsG)
{
    __shared__ __align__(16) float row[VD];
    __shared__ float red[DD];
    int n = blockIdx.x, t = threadIdx.x;
    if (n < GG) flagsG[n*NND + t] = 0;          // level-barrier flags for k_treeX
    int id = data[n];
    const float4* vp = (const float4*)(vecs + (size_t)id * VD);  // 1200B rows
    for (int i = t; i < VD/4; i += 128) ((float4*)row)[i] = vp[i];
    __syncthreads();
    float a0 = db[t], a1 = 0.f, a2 = 0.f, a3 = 0.f;
    for (int d = 0; d < VD; d += 4){
        a0 = fmaf(row[d+0], dw[(d+0)*DD + t], a0);
        a1 = fmaf(row[d+1], dw[(d+1)*DD + t], a1);
        a2 = fmaf(row[d+2], dw[(d+2)*DD + t], a2);
        a3 = fmaf(row[d+3], dw[(d+3)*DD + t], a3);
    }
    float acc = (a0 + a1) + (a2 + a3);
    base[n*DD + t] = acc;
    if (n == posArr[0]){
        red[t] = acc * sdw[t];
        __syncthreads();
        for (int o = 64; o > 0; o >>= 1){ if (t < o) red[t] += red[t+o]; __syncthreads(); }
        if (t == 0) dscore[0] = sb[0] + red[0];
    }
}

// ---------------- K2: multi-CU level-synchronous tree sweep ----------------
__global__ void __launch_bounds__(1024, 1) k_treeX(
        const int* __restrict__ graphs, const int* __restrict__ edges,
        const int* __restrict__ posArr, const float* __restrict__ EW,
        const float* __restrict__ EB,   const float* __restrict__ base,
        float* __restrict__ vposG, float* __restrict__ uG, int* __restrict__ meta,
        float* __restrict__ contribX, int* __restrict__ flagsG)
{
    __shared__ __align__(16) float xstage[16][DD];       // per-wave emb stage, 8KB
    __shared__ int par_s[NND], eid_s[NND], flg_s[NND];
    __shared__ int ccnt[NND], cstart[NND], cidx[NND];
    __shared__ int dep[NND], anc[NND], lcnt[NND], lstart[NND], order[NND];
    __shared__ int maxD_s;

    int b = blockIdx.x, g = b >> 3, k = b & (KSP-1), t = threadIdx.x;

    // ---- phase 1: load graph structure (identical in all 8 blocks of g) ----
    if (t < NND){
        par_s[t] = (t < NND-1) ? (t + graphs[g*NND + t]) : (NND-1);  // root self-parent
        eid_s[t] = edges[t];
        flg_s[t] = 0;
        ccnt[t]  = 0;
        lcnt[t]  = 0;
    }
    if (t == 0) maxD_s = 0;
    __syncthreads();

    // ---- phase 2: child counts, sibling slots, path walk ----
    int mySlot = 0;
    if (t < NND-1){
        int p = par_s[t];
        atomicAdd(&ccnt[p], 1);
        for (int c = 0; c < t; ++c) mySlot += (par_s[c] == p);  // ascending order
    }
    if (t < NND){
        dep[t] = (t < NND-1) ? 1 : 0;
        anc[t] = par_s[t];
    }
    if (t == 0){
        int p = posArr[0];
        flg_s[p] |= F_POS;
        int c = par_s[p], s = 0;
        for (;;){
            flg_s[c] |= F_PATH | (s << 24);
            if (k == 0) meta[g*(NND+1) + 1 + s] = c;
            ++s;
            if (c == NND-1) break;
            c = par_s[c];
        }
        if (k == 0) meta[g*(NND+1)] = s;            // path length L
    }
    __syncthreads();

    // ---- phase 3: child list offsets ----
    if (t < NND){
        int s = 0;
        for (int p = 0; p < t; ++p) s += ccnt[p];
        cstart[t] = s;
    }
    __syncthreads();
    if (t < NND-1) cidx[cstart[par_s[t]] + mySlot] = t;

    // ---- phase 4: depth via pointer jumping ----
    for (int kk = 0; kk < 7; ++kk){
        int d2 = 0, a2 = 0;
        if (t < NND){ d2 = dep[t] + dep[anc[t]]; a2 = anc[anc[t]]; }
        __syncthreads();
        if (t < NND){ dep[t] = d2; anc[t] = a2; }
        __syncthreads();
    }
    if (t < NND) atomicMax(&maxD_s, dep[t]);
    if (t < NND) atomicAdd(&lcnt[dep[t]], 1);
    __syncthreads();

    // ---- phase 5: bucket nodes by depth (deterministic, same in all blocks) ----
    if (t < NND){
        int s = 0;
        for (int d2 = 0; d2 < t; ++d2) s += lcnt[d2];
        lstart[t] = s;
    }
    __syncthreads();
    if (t < NND){
        int d2 = dep[t], s = 0;
        for (int c = 0; c < t; ++c) s += (dep[c] == d2);
        order[lstart[d2] + s] = t;
    }
    __syncthreads();

    // ---- main: levels deepest..root; node q of a level -> block (q mod 8) ----
    int w = t >> 6, l = t & 63;
    int c0 = 2*l;                       // gather/stage mapping: 2 cols/lane
    int li = l & 31, hl = l >> 5;       // GEMV mapping: 4 cols x half-d
    int c4 = 4*li, dbase = 64*hl;
    int maxD = maxD_s;

    // touch all 512 x 128B lines of next-level node's W (read-only prefetch;
    // values kept live via empty asm -> no DCE, no math change)
    auto prefetchL = [&](int dl){
        int lo2 = lstart[dl], cnt2 = lcnt[dl];
        for (int q2 = k + KSP*w; q2 < cnt2; q2 += KSP*16){
            int n2 = order[lo2 + q2];
            if (flg_s[n2] & SKIPF) continue;
            const float* Pp = EW + (size_t)eid_s[n2]*(DD*DD);
            #pragma unroll
            for (int j = 0; j < 8; ++j){
                float v = Pp[(size_t)(l + 64*j)*32];   // one float per 128B line
                asm volatile("" :: "v"(v));
            }
        }
    };

    for (int d = maxD; d >= 0; --d){
        int lo = lstart[d], cnt = lcnt[d];
        for (int q = k + KSP*w; q < cnt; q += KSP*16){
            int n = order[lo + q];                  // wave-uniform
            // gather: base + non-path child contribs (ascending, 4-wide batches)
            float2 bse = *(const float2*)&base[n*DD + c0];
            float e0 = bse.x, e1 = bse.y;
            int cs = cstart[n], cc = ccnt[n];
            for (int j0 = 0; j0 < cc; j0 += 4){
                float2 v0, v1, v2, v3;
                int u0=0, u1=0, u2=0, u3=0;
                if (j0+0 < cc){ int c = cidx[cs+j0+0];
                    if (!(flg_s[c] & SKIPF)){ v0 = *(const float2*)&contribX[((size_t)g*NND+c)*DD + c0]; u0=1; } }
                if (j0+1 < cc){ int c = cidx[cs+j0+1];
                    if (!(flg_s[c] & SKIPF)){ v1 = *(const float2*)&contribX[((size_t)g*NND+c)*DD + c0]; u1=1; } }
                if (j0+2 < cc){ int c = cidx[cs+j0+2];
                    if (!(flg_s[c] & SKIPF)){ v2 = *(const float2*)&contribX[((size_t)g*NND+c)*DD + c0]; u2=1; } }
                if (j0+3 < cc){ int c = cidx[cs+j0+3];
                    if (!(flg_s[c] & SKIPF)){ v3 = *(const float2*)&contribX[((size_t)g*NND+c)*DD + c0]; u3=1; } }
                if (u0){ e0 += v0.x; e1 += v0.y; }   // strictly j-ascending order
                if (u1){ e0 += v1.x; e1 += v1.y; }
                if (u2){ e0 += v2.x; e1 += v2.y; }
                if (u3){ e0 += v3.x; e1 += v3.y; }
            }
            int f = flg_s[n];
            if (f & F_POS){
                if (cc){ e0 = fmaxf(e0, 0.f); e1 = fmaxf(e1, 0.f); }
                *(float2*)&vposG[g*DD + c0] = make_float2(e0, e1);
            } else if (f & F_PATH){
                int slot = ((u32)f) >> 24;
                *(float2*)&uG[((size_t)g*NND + slot)*DD + c0] = make_float2(e0, e1);  // pre-relu
            } else {
                if (cc){ e0 = fmaxf(e0, 0.f); e1 = fmaxf(e1, 0.f); }
                *(float2*)&xstage[w][c0] = make_float2(e0, e1);       // stage emb
                asm volatile("s_waitcnt lgkmcnt(0)" ::: "memory");    // wave-internal RAW
                int e = eid_s[n];
                const float* Wp = EW + (size_t)e*(DD*DD) + (size_t)dbase*DD + c4;
                const float* xr = &xstage[w][dbase];
                float4 A[8], B[8];
                float s0=0.f, s1=0.f, s2=0.f, s3=0.f;
                #define LW(buf, gi) { _Pragma("unroll") \
                    for (int j2 = 0; j2 < 8; ++j2) \
                        buf[j2] = *(const float4*)&Wp[(size_t)((gi)*8 + j2)*DD]; }
                #define CP(buf, gi) { _Pragma("unroll") \
                    for (int j2 = 0; j2 < 8; ++j2){ \
                        float x = xr[(gi)*8 + j2]; \
                        s0 = fmaf(x, buf[j2].x, s0); s1 = fmaf(x, buf[j2].y, s1); \
                        s2 = fmaf(x, buf[j2].z, s2); s3 = fmaf(x, buf[j2].w, s3); } }
                LW(A,0); LW(B,1);
                CP(A,0); LW(A,2);
                CP(B,1); LW(B,3);
                CP(A,2); LW(A,4);
                CP(B,3); LW(B,5);
                CP(A,4); LW(A,6);
                CP(B,5); LW(B,7);
                CP(A,6);
                CP(B,7);
                #undef LW
                #undef CP
                s0 += __shfl_xor(s0, 32); s1 += __shfl_xor(s1, 32);
                s2 += __shfl_xor(s2, 32); s3 += __shfl_xor(s3, 32);
                if (hl == 0){
                    float4 bb = *(const float4*)&EB[(size_t)e*DD + c4];
                    *(float4*)&contribX[((size_t)g*NND + n)*DD + c4] =
                        make_float4(s0 + bb.x, s1 + bb.y, s2 + bb.z, s3 + bb.w);
                }
            }
        }
        if (d > 0) prefetchL(d-1);                   // overlap next level's W fetch
        __syncthreads();
        if (d > 0){                                  // 8-block level barrier
            if (t == 0){
                __threadfence();                     // release block's contrib stores
                atomicAdd(&flagsG[g*NND + d], 1);
                while (__hip_atomic_load(&flagsG[g*NND + d],
                        __ATOMIC_ACQUIRE, __HIP_MEMORY_SCOPE_AGENT) < KSP)
                    __builtin_amdgcn_s_sleep(1);
                __threadfence();                     // acquire others' stores
            }
            __syncthreads();
        }
    }
}

// ---------------- K3a: step 0, batched over graphs ----------------
__global__ void __launch_bounds__(256, 1) k_step0(
        const float* __restrict__ EW, const float* __restrict__ EB,
        const float* __restrict__ vposG, const float* __restrict__ uG,
        float* __restrict__ V0)
{
    __shared__ __align__(16) float vpos_s[GG][DD];
    int e = blockIdx.x, t = threadIdx.x, l = t & 63, w = t >> 6;
    {
        int idx = t;                                 // GG*DD/4 == 256 exactly
        ((float4*)vpos_s)[idx] = ((const float4*)vposG)[idx];
    }
    __syncthreads();
    int k4 = w*8 + (l & 7);
    int d0 = (l >> 3) * 16;
    bool owner = ((l >> 3) == 0);
    const float* Wp = EW + (size_t)e*(DD*DD) + (size_t)d0*DD + 4*k4;
    float4 wr[16];
    #pragma unroll
    for (int d = 0; d < 16; ++d) wr[d] = *(const float4*)&Wp[d*DD];
    float4 bb = *(const float4*)&EB[(size_t)e*DD + 4*k4];
    for (int g = 0; g < GG; ++g){
        float s0=0.f, s1=0.f, s2=0.f, s3=0.f;
        #pragma unroll
        for (int d = 0; d < 16; ++d){
            float x = vpos_s[g][d0 + d];
            s0 = fmaf(x, wr[d].x, s0);
            s1 = fmaf(x, wr[d].y, s1);
            s2 = fmaf(x, wr[d].z, s2);
            s3 = fmaf(x, wr[d].w, s3);
        }
        #pragma unroll
        for (int m = 8; m <= 32; m <<= 1){
            s0 += __shfl_xor(s0, m); s1 += __shfl_xor(s1, m);
            s2 += __shfl_xor(s2, m); s3 += __shfl_xor(s3, m);
        }
        if (owner){
            float4 u0 = *(const float4*)&uG[(size_t)g*NND*DD + 4*k4];
            float4 r;
            r.x = fmaxf(u0.x + s0 + bb.x, 0.f);
            r.y = fmaxf(u0.y + s1 + bb.y, 0.f);
            r.z = fmaxf(u0.z + s2 + bb.z, 0.f);
            r.w = fmaxf(u0.w + s3 + bb.w, 0.f);
            *(float4*)&V0[((size_t)g*EDGEN + e)*DD + 4*k4] = r;
        }
    }
}

// ---------------- K3b: path chains, 16 e-rows per block ----------------
__global__ void __launch_bounds__(256, 1) k_steps(
        const int* __restrict__ edges,
        const float* __restrict__ EW, const float* __restrict__ EB,
        const float* __restrict__ SEW,
        const float* __restrict__ uG, const float* __restrict__ V0,
        const int* __restrict__ meta, const float* __restrict__ dscore,
        float* __restrict__ outp)
{
    __shared__ __align__(16) float Vbuf[2][CH2][DD];
    __shared__ float red[CH2][4];
    int g = blockIdx.x >> 3, chunk = blockIdx.x & 7;
    int t = threadIdx.x, l = t & 63, w = t >> 6;
    int k4 = w*8 + (l & 7);
    int d0 = (l >> 3) * 16;
    bool owner = ((l >> 3) == 0);
    int eBase = chunk * CH2;
    int L = meta[g*(NND+1)];

    // load this block's 16 step-0 rows
    for (int idx = t; idx < CH2*DD/4; idx += 256)
        ((float4*)&Vbuf[0][0][0])[idx] =
            ((const float4*)&V0[((size_t)g*EDGEN + eBase)*DD])[idx];
    __syncthreads();

    // ---- shared steps 1..L-1: one W per step, reused across CH2 e-rows ----
    int cur = 0;
    for (int s = 1; s < L; ++s){
        int pn = meta[g*(NND+1) + s];           // path[s-1]
        int ej = edges[pn];
        const float* Wp = EW + (size_t)ej*(DD*DD) + (size_t)d0*DD + 4*k4;
        float4 wr[16];
        #pragma unroll
        for (int d = 0; d < 16; ++d) wr[d] = *(const float4*)&Wp[d*DD];
        float4 us = *(const float4*)&uG[((size_t)g*NND + s)*DD + 4*k4];
        float4 bb = *(const float4*)&EB[(size_t)ej*DD + 4*k4];
        #pragma unroll 4
        for (int p = 0; p < CH2; ++p){
            float ev[16];
            #pragma unroll
            for (int j = 0; j < 4; ++j){
                float4 x = *(const float4*)&Vbuf[cur][p][d0 + 4*j];
                ev[4*j+0]=x.x; ev[4*j+1]=x.y; ev[4*j+2]=x.z; ev[4*j+3]=x.w;
            }
            float s0=0.f, s1=0.f, s2=0.f, s3=0.f;
            #pragma unroll
            for (int d = 0; d < 16; ++d){
                s0 = fmaf(ev[d], wr[d].x, s0);
                s1 = fmaf(ev[d], wr[d].y, s1);
                s2 = fmaf(ev[d], wr[d].z, s2);
                s3 = fmaf(ev[d], wr[d].w, s3);
            }
            #pragma unroll
            for (int m = 8; m <= 32; m <<= 1){
                s0 += __shfl_xor(s0, m); s1 += __shfl_xor(s1, m);
                s2 += __shfl_xor(s2, m); s3 += __shfl_xor(s3, m);
            }
            if (owner){
                float4 r;
                r.x = fmaxf(us.x + s0 + bb.x, 0.f);
                r.y = fmaxf(us.y + s1 + bb.y, 0.f);
                r.z = fmaxf(us.z + s2 + bb.z, 0.f);
                r.w = fmaxf(us.w + s3 + bb.w, 0.f);
                *(float4*)&Vbuf[cur^1][p][4*k4] = r;
            }
        }
        __syncthreads();
        cur ^= 1;
    }

    // ---- final transform (root edge) + score ----
    {
        int rn = meta[g*(NND+1) + L];           // path[L-1] (= 127)
        int er = edges[rn];
        const float* Wp = EW + (size_t)er*(DD*DD) + (size_t)d0*DD + 4*k4;
        float4 wr[16];
        #pragma unroll
        for (int d = 0; d < 16; ++d) wr[d] = *(const float4*)&Wp[d*DD];
        float4 bb = *(const float4*)&EB[(size_t)er*DD + 4*k4];
        float4 sw = *(const float4*)&SEW[4*k4];
        #pragma unroll 4
        for (int p = 0; p < CH2; ++p){
            float ev[16];
            #pragma unroll
            for (int j = 0; j < 4; ++j){
                float4 x = *(const float4*)&Vbuf[cur][p][d0 + 4*j];
                ev[4*j+0]=x.x; ev[4*j+1]=x.y; ev[4*j+2]=x.z; ev[4*j+3]=x.w;
            }
            float s0=0.f, s1=0.f, s2=0.f, s3=0.f;
            #pragma unroll
            for (int d = 0; d < 16; ++d){
                s0 = fmaf(ev[d], wr[d].x, s0);
                s1 = fmaf(ev[d], wr[d].y, s1);
                s2 = fmaf(ev[d], wr[d].z, s2);
                s3 = fmaf(ev[d], wr[d].w, s3);
            }
            #pragma unroll
            for (int m = 8; m <= 32; m <<= 1){
                s0 += __shfl_xor(s0, m); s1 += __shfl_xor(s1, m);
                s2 += __shfl_xor(s2, m); s3 += __shfl_xor(s3, m);
            }
            if (owner){
                float part = (s0 + bb.x) * sw.x + (s1 + bb.y) * sw.y
                           + (s2 + bb.z) * sw.z + (s3 + bb.w) * sw.w;
                part += __shfl_xor(part, 1);
                part += __shfl_xor(part, 2);
                part += __shfl_xor(part, 4);
                if (l == 0) red[p][w] = part;
            }
        }
        __syncthreads();
        if (t < CH2)
            outp[g*DD + eBase + t] = dscore[0] + red[t][0] + red[t][1] + red[t][2] + red[t][3];
    }
}

extern "C" void kernel_launch(void* const* d_in, const int* in_sizes, int n_in,
                              void* d_out, int out_size, void* d_ws, size_t ws_size,
                              hipStream_t stream)
{
    const int*   data   = (const int*)d_in[0];
    /* d_in[1] = types, unused (single data_type) */
    const int*   graphs = (const int*)d_in[2];
    const int*   edges  = (const int*)d_in[3];
    const int*   posArr = (const int*)d_in[4];
    const float* vecs   = (const float*)d_in[5];
    const float* dw     = (const float*)d_in[6];
    const float* db     = (const float*)d_in[7];
    const float* ew     = (const float*)d_in[8];
    const float* eb     = (const float*)d_in[9];
    const float* sew    = (const float*)d_in[10];
    const float* sdw    = (const float*)d_in[11];
    const float* sb     = (const float*)d_in[12];

    char* ws = (char*)d_ws;
    float* base   = (float*)(ws);                               // 64 KB
    float* vposG  = (float*)(ws + 65536);                       // 4 KB
    float* uG     = (float*)(ws + 69632);                       // 512 KB
    float* dscore = (float*)(ws + 593920);                      // 1 f32
    int*   meta   = (int*)  (ws + 594176);                      // 8*129 ints
    float* V0     = (float*)(ws + 598528);                      // 512 KB (k_step0->k_steps)
    float* contribX = V0;                                       // overlay: dead before k_step0
    int*   flagsG = (int*)  (ws + 1122816);                     // 8*128 ints

    float* outp = (float*)d_out;

    k_base <<<NND, 128, 0, stream>>>(data, posArr, vecs, dw, db, sdw, sb,
                                     base, dscore, flagsG);
    k_treeX<<<GG*KSP, 1024, 0, stream>>>(graphs, edges, posArr, ew, eb, base,
                                         vposG, uG, meta, contribX, flagsG);
    k_step0<<<EDGEN, 256, 0, stream>>>(ew, eb, vposG, uG, V0);
    k_steps<<<GG*(EDGEN/CH2), 256, 0, stream>>>(edges, ew, eb, sew, uG, V0,
                                                meta, dscore, outp);
}

// Round 10
// 318.366 us; speedup vs baseline: 1.0682x; 1.0682x over previous
//
#include <hip/hip_runtime.h>
#include <stdint.h>

// Net_49177375539428: recursive tree-NN scorer, all-fp32.
//   k_base : base GEMV + d_score + flag zeroing (round-7 verbatim).
//   k_treeX: multi-CU level-synchronous tree sweep (round-7 structure,
//            79us validated) with a DEEP ASM GEMV PIPELINE:
//            512 thr (8 waves) per block -> VGPR budget 256 -> 5 buffer
//            sets x 8 float4 = 40 loads in flight (R7's compiled code held
//            ~16 -> GEMV ~2.3us latency-bound; 40 deep -> ~0.7us).
//            Rolling s_waitcnt vmcnt(32..0) + sched_barrier(0) (rule #18).
//            vmcnt(0) drain at GEMV entry: contribX/uG/vposG are GLOBAL
//            stores that pollute vmcnt counting. Consume order strictly
//            d-ascending per half + shfl_xor(32) -> bit-identical math.
//            (R9 fix: parenthesized token-paste (B##2).x — `2.x` lexes as
//            one pp-number so B##2.x formed an invalid token.)
//   k_step0: one block per edge-type e (round-7 verbatim).
//   k_steps: path chain, 16 e-rows per block (round-7 verbatim).

#define NND 128
#define DD  128
#define GG  8
#define VD  300
#define EDGEN 128
#define CH2 16         // e-rows per k_steps block
#define KSP 8          // blocks per graph in k_treeX

typedef unsigned int u32;

#define F_POS  (1<<16)
#define F_PATH (1<<17)
#define SKIPF  (F_POS|F_PATH)

// ---------------- K1: base embeddings + d_score + flag zero ----------------
__global__ void __launch_bounds__(128) k_base(
        const int* __restrict__ data, const int* __restrict__ posArr,
        const float* __restrict__ vecs, const float* __restrict__ dw,
        const float* __restrict__ db,   const float* __restrict__ sdw,
        const float* __restrict__ sb,
        float* __restrict__ base, float* __restrict__ dscore,
        int* __restrict__ flagsG)
{
    __shared__ __align__(16) float row[VD];
    __shared__ float red[DD];
    int n = blockIdx.x, t = threadIdx.x;
    if (n < GG) flagsG[n*NND + t] = 0;          // level-barrier flags for k_treeX
    int id = data[n];
    const float4* vp = (const float4*)(vecs + (size_t)id * VD);  // 1200B rows
    for (int i = t; i < VD/4; i += 128) ((float4*)row)[i] = vp[i];
    __syncthreads();
    float a0 = db[t], a1 = 0.f, a2 = 0.f, a3 = 0.f;
    for (int d = 0; d < VD; d += 4){
        a0 = fmaf(row[d+0], dw[(d+0)*DD + t], a0);
        a1 = fmaf(row[d+1], dw[(d+1)*DD + t], a1);
        a2 = fmaf(row[d+2], dw[(d+2)*DD + t], a2);
        a3 = fmaf(row[d+3], dw[(d+3)*DD + t], a3);
    }
    float acc = (a0 + a1) + (a2 + a3);
    base[n*DD + t] = acc;
    if (n == posArr[0]){
        red[t] = acc * sdw[t];
        __syncthreads();
        for (int o = 64; o > 0; o >>= 1){ if (t < o) red[t] += red[t+o]; __syncthreads(); }
        if (t == 0) dscore[0] = sb[0] + red[0];
    }
}

// ---------------- K2: multi-CU level-synchronous tree sweep ----------------
__global__ void __launch_bounds__(512, 1) k_treeX(
        const int* __restrict__ graphs, const int* __restrict__ edges,
        const int* __restrict__ posArr, const float* __restrict__ EW,
        const float* __restrict__ EB,   const float* __restrict__ base,
        float* __restrict__ vposG, float* __restrict__ uG, int* __restrict__ meta,
        float* __restrict__ contribX, int* __restrict__ flagsG)
{
    __shared__ __align__(16) float xstage[8][DD];        // per-wave emb stage, 4KB
    __shared__ int par_s[NND], eid_s[NND], flg_s[NND];
    __shared__ int ccnt[NND], cstart[NND], cidx[NND];
    __shared__ int dep[NND], anc[NND], lcnt[NND], lstart[NND], order[NND];
    __shared__ int maxD_s;

    int b = blockIdx.x, g = b >> 3, k = b & (KSP-1), t = threadIdx.x;

    // ---- phase 1: load graph structure (identical in all 8 blocks of g) ----
    if (t < NND){
        par_s[t] = (t < NND-1) ? (t + graphs[g*NND + t]) : (NND-1);  // root self-parent
        eid_s[t] = edges[t];
        flg_s[t] = 0;
        ccnt[t]  = 0;
        lcnt[t]  = 0;
    }
    if (t == 0) maxD_s = 0;
    __syncthreads();

    // ---- phase 2: child counts, sibling slots, path walk ----
    int mySlot = 0;
    if (t < NND-1){
        int p = par_s[t];
        atomicAdd(&ccnt[p], 1);
        for (int c = 0; c < t; ++c) mySlot += (par_s[c] == p);  // ascending order
    }
    if (t < NND){
        dep[t] = (t < NND-1) ? 1 : 0;
        anc[t] = par_s[t];
    }
    if (t == 0){
        int p = posArr[0];
        flg_s[p] |= F_POS;
        int c = par_s[p], s = 0;
        for (;;){
            flg_s[c] |= F_PATH | (s << 24);
            if (k == 0) meta[g*(NND+1) + 1 + s] = c;
            ++s;
            if (c == NND-1) break;
            c = par_s[c];
        }
        if (k == 0) meta[g*(NND+1)] = s;            // path length L
    }
    __syncthreads();

    // ---- phase 3: child list offsets ----
    if (t < NND){
        int s = 0;
        for (int p = 0; p < t; ++p) s += ccnt[p];
        cstart[t] = s;
    }
    __syncthreads();
    if (t < NND-1) cidx[cstart[par_s[t]] + mySlot] = t;

    // ---- phase 4: depth via pointer jumping ----
    for (int kk = 0; kk < 7; ++kk){
        int d2 = 0, a2 = 0;
        if (t < NND){ d2 = dep[t] + dep[anc[t]]; a2 = anc[anc[t]]; }
        __syncthreads();
        if (t < NND){ dep[t] = d2; anc[t] = a2; }
        __syncthreads();
    }
    if (t < NND) atomicMax(&maxD_s, dep[t]);
    if (t < NND) atomicAdd(&lcnt[dep[t]], 1);
    __syncthreads();

    // ---- phase 5: bucket nodes by depth (deterministic, same in all blocks) ----
    if (t < NND){
        int s = 0;
        for (int d2 = 0; d2 < t; ++d2) s += lcnt[d2];
        lstart[t] = s;
    }
    __syncthreads();
    if (t < NND){
        int d2 = dep[t], s = 0;
        for (int c = 0; c < t; ++c) s += (dep[c] == d2);
        order[lstart[d2] + s] = t;
    }
    __syncthreads();

    // ---- main: levels deepest..root; node q of a level -> block (q mod 8) ----
    int w = t >> 6, l = t & 63;                 // 8 waves
    int c0 = 2*l;                       // gather/stage mapping: 2 cols/lane
    int li = l & 31, hl = l >> 5;       // GEMV mapping: 4 cols x half-d
    int c4 = 4*li, dbase = 64*hl;
    int maxD = maxD_s;

    for (int d = maxD; d >= 0; --d){
        int lo = lstart[d], cnt = lcnt[d];
        for (int q = k + KSP*w; q < cnt; q += KSP*8){
            int n = order[lo + q];                  // wave-uniform
            // gather: base + non-path child contribs (ascending, 4-wide batches)
            float2 bse = *(const float2*)&base[n*DD + c0];
            float e0 = bse.x, e1 = bse.y;
            int cs = cstart[n], cc = ccnt[n];
            for (int j0 = 0; j0 < cc; j0 += 4){
                float2 v0, v1, v2, v3;
                int u0=0, u1=0, u2=0, u3=0;
                if (j0+0 < cc){ int c = cidx[cs+j0+0];
                    if (!(flg_s[c] & SKIPF)){ v0 = *(const float2*)&contribX[((size_t)g*NND+c)*DD + c0]; u0=1; } }
                if (j0+1 < cc){ int c = cidx[cs+j0+1];
                    if (!(flg_s[c] & SKIPF)){ v1 = *(const float2*)&contribX[((size_t)g*NND+c)*DD + c0]; u1=1; } }
                if (j0+2 < cc){ int c = cidx[cs+j0+2];
                    if (!(flg_s[c] & SKIPF)){ v2 = *(const float2*)&contribX[((size_t)g*NND+c)*DD + c0]; u2=1; } }
                if (j0+3 < cc){ int c = cidx[cs+j0+3];
                    if (!(flg_s[c] & SKIPF)){ v3 = *(const float2*)&contribX[((size_t)g*NND+c)*DD + c0]; u3=1; } }
                if (u0){ e0 += v0.x; e1 += v0.y; }   // strictly j-ascending order
                if (u1){ e0 += v1.x; e1 += v1.y; }
                if (u2){ e0 += v2.x; e1 += v2.y; }
                if (u3){ e0 += v3.x; e1 += v3.y; }
            }
            int f = flg_s[n];
            if (f & F_POS){
                if (cc){ e0 = fmaxf(e0, 0.f); e1 = fmaxf(e1, 0.f); }
                *(float2*)&vposG[g*DD + c0] = make_float2(e0, e1);
            } else if (f & F_PATH){
                int slot = ((u32)f) >> 24;
                *(float2*)&uG[((size_t)g*NND + slot)*DD + c0] = make_float2(e0, e1);  // pre-relu
            } else {
                if (cc){ e0 = fmaxf(e0, 0.f); e1 = fmaxf(e1, 0.f); }
                *(float2*)&xstage[w][c0] = make_float2(e0, e1);       // stage emb
                asm volatile("s_waitcnt lgkmcnt(0)" ::: "memory");    // wave-internal RAW
                int e = eid_s[n];
                const float* Wp = EW + (size_t)e*(DD*DD) + (size_t)dbase*DD + c4;
                const float* xr = &xstage[w][dbase];
                float s0=0.f, s1=0.f, s2=0.f, s3=0.f;
                float4 Pa0,Pa1,Pa2,Pa3,Pa4,Pa5,Pa6,Pa7;
                float4 Pb0,Pb1,Pb2,Pb3,Pb4,Pb5,Pb6,Pb7;
                float4 Pc0,Pc1,Pc2,Pc3,Pc4,Pc5,Pc6,Pc7;
                float4 Pd0,Pd1,Pd2,Pd3,Pd4,Pd5,Pd6,Pd7;
                float4 Pe0,Pe1,Pe2,Pe3,Pe4,Pe5,Pe6,Pe7;
#define GISS(B, pp) \
    asm volatile("global_load_dwordx4 %0, %8, off\n\t" \
                 "global_load_dwordx4 %1, %8, off offset:512\n\t" \
                 "global_load_dwordx4 %2, %8, off offset:1024\n\t" \
                 "global_load_dwordx4 %3, %8, off offset:1536\n\t" \
                 "global_load_dwordx4 %4, %8, off offset:2048\n\t" \
                 "global_load_dwordx4 %5, %8, off offset:2560\n\t" \
                 "global_load_dwordx4 %6, %8, off offset:3072\n\t" \
                 "global_load_dwordx4 %7, %8, off offset:3584" \
                 : "=&v"(B##0),"=&v"(B##1),"=&v"(B##2),"=&v"(B##3), \
                   "=&v"(B##4),"=&v"(B##5),"=&v"(B##6),"=&v"(B##7) : "v"(pp))
#define GW(n) do { asm volatile("s_waitcnt vmcnt(" #n ")" ::: "memory"); \
                   __builtin_amdgcn_sched_barrier(0); } while(0)
#define GCONS(B, kk) do { \
    float4 xa = *(const float4*)&xr[(kk)*8]; \
    float4 xb = *(const float4*)&xr[(kk)*8 + 4]; \
    s0=fmaf(xa.x,(B##0).x,s0); s1=fmaf(xa.x,(B##0).y,s1); s2=fmaf(xa.x,(B##0).z,s2); s3=fmaf(xa.x,(B##0).w,s3); \
    s0=fmaf(xa.y,(B##1).x,s0); s1=fmaf(xa.y,(B##1).y,s1); s2=fmaf(xa.y,(B##1).z,s2); s3=fmaf(xa.y,(B##1).w,s3); \
    s0=fmaf(xa.z,(B##2).x,s0); s1=fmaf(xa.z,(B##2).y,s1); s2=fmaf(xa.z,(B##2).z,s2); s3=fmaf(xa.z,(B##2).w,s3); \
    s0=fmaf(xa.w,(B##3).x,s0); s1=fmaf(xa.w,(B##3).y,s1); s2=fmaf(xa.w,(B##3).z,s2); s3=fmaf(xa.w,(B##3).w,s3); \
    s0=fmaf(xb.x,(B##4).x,s0); s1=fmaf(xb.x,(B##4).y,s1); s2=fmaf(xb.x,(B##4).z,s2); s3=fmaf(xb.x,(B##4).w,s3); \
    s0=fmaf(xb.y,(B##5).x,s0); s1=fmaf(xb.y,(B##5).y,s1); s2=fmaf(xb.y,(B##5).z,s2); s3=fmaf(xb.y,(B##5).w,s3); \
    s0=fmaf(xb.z,(B##6).x,s0); s1=fmaf(xb.z,(B##6).y,s1); s2=fmaf(xb.z,(B##6).z,s2); s3=fmaf(xb.z,(B##6).w,s3); \
    s0=fmaf(xb.w,(B##7).x,s0); s1=fmaf(xb.w,(B##7).y,s1); s2=fmaf(xb.w,(B##7).z,s2); s3=fmaf(xb.w,(B##7).w,s3); \
    } while(0)
                // drain outstanding global STORES (contribX/uG/vposG) so the
                // rolling vmcnt counts below are exact
                asm volatile("s_waitcnt vmcnt(0)" ::: "memory");
                __builtin_amdgcn_sched_barrier(0);
                GISS(Pa, Wp);
                GISS(Pb, Wp + 1024);
                GISS(Pc, Wp + 2048);
                GISS(Pd, Wp + 3072);
                GISS(Pe, Wp + 4096);
                GW(32); GCONS(Pa, 0); GISS(Pa, Wp + 5120);
                GW(32); GCONS(Pb, 1); GISS(Pb, Wp + 6144);
                GW(32); GCONS(Pc, 2); GISS(Pc, Wp + 7168);
                GW(24); GCONS(Pd, 3);
                GW(16); GCONS(Pe, 4);
                GW(8);  GCONS(Pa, 5);
                GW(4);  GCONS(Pb, 6);
                GW(0);  GCONS(Pc, 7);
#undef GISS
#undef GW
#undef GCONS
                s0 += __shfl_xor(s0, 32); s1 += __shfl_xor(s1, 32);
                s2 += __shfl_xor(s2, 32); s3 += __shfl_xor(s3, 32);
                if (hl == 0){
                    float4 bb = *(const float4*)&EB[(size_t)e*DD + c4];
                    *(float4*)&contribX[((size_t)g*NND + n)*DD + c4] =
                        make_float4(s0 + bb.x, s1 + bb.y, s2 + bb.z, s3 + bb.w);
                }
            }
        }
        __syncthreads();
        if (d > 0){                                  // 8-block level barrier
            if (t == 0){
                __threadfence();                     // release block's contrib stores
                atomicAdd(&flagsG[g*NND + d], 1);
                while (__hip_atomic_load(&flagsG[g*NND + d],
                        __ATOMIC_ACQUIRE, __HIP_MEMORY_SCOPE_AGENT) < KSP)
                    __builtin_amdgcn_s_sleep(1);
                __threadfence();                     // acquire others' stores
            }
            __syncthreads();
        }
    }
}

// ---------------- K3a: step 0, batched over graphs ----------------
__global__ void __launch_bounds__(256, 1) k_step0(
        const float* __restrict__ EW, const float* __restrict__ EB,
        const float* __restrict__ vposG, const float* __restrict__ uG,
        float* __restrict__ V0)
{
    __shared__ __align__(16) float vpos_s[GG][DD];
    int e = blockIdx.x, t = threadIdx.x, l = t & 63, w = t >> 6;
    {
        int idx = t;                                 // GG*DD/4 == 256 exactly
        ((float4*)vpos_s)[idx] = ((const float4*)vposG)[idx];
    }
    __syncthreads();
    int k4 = w*8 + (l & 7);
    int d0 = (l >> 3) * 16;
    bool owner = ((l >> 3) == 0);
    const float* Wp = EW + (size_t)e*(DD*DD) + (size_t)d0*DD + 4*k4;
    float4 wr[16];
    #pragma unroll
    for (int d = 0; d < 16; ++d) wr[d] = *(const float4*)&Wp[d*DD];
    float4 bb = *(const float4*)&EB[(size_t)e*DD + 4*k4];
    for (int g = 0; g < GG; ++g){
        float s0=0.f, s1=0.f, s2=0.f, s3=0.f;
        #pragma unroll
        for (int d = 0; d < 16; ++d){
            float x = vpos_s[g][d0 + d];
            s0 = fmaf(x, wr[d].x, s0);
            s1 = fmaf(x, wr[d].y, s1);
            s2 = fmaf(x, wr[d].z, s2);
            s3 = fmaf(x, wr[d].w, s3);
        }
        #pragma unroll
        for (int m = 8; m <= 32; m <<= 1){
            s0 += __shfl_xor(s0, m); s1 += __shfl_xor(s1, m);
            s2 += __shfl_xor(s2, m); s3 += __shfl_xor(s3, m);
        }
        if (owner){
            float4 u0 = *(const float4*)&uG[(size_t)g*NND*DD + 4*k4];
            float4 r;
            r.x = fmaxf(u0.x + s0 + bb.x, 0.f);
            r.y = fmaxf(u0.y + s1 + bb.y, 0.f);
            r.z = fmaxf(u0.z + s2 + bb.z, 0.f);
            r.w = fmaxf(u0.w + s3 + bb.w, 0.f);
            *(float4*)&V0[((size_t)g*EDGEN + e)*DD + 4*k4] = r;
        }
    }
}

// ---------------- K3b: path chains, 16 e-rows per block ----------------
__global__ void __launch_bounds__(256, 1) k_steps(
        const int* __restrict__ edges,
        const float* __restrict__ EW, const float* __restrict__ EB,
        const float* __restrict__ SEW,
        const float* __restrict__ uG, const float* __restrict__ V0,
        const int* __restrict__ meta, const float* __restrict__ dscore,
        float* __restrict__ outp)
{
    __shared__ __align__(16) float Vbuf[2][CH2][DD];
    __shared__ float red[CH2][4];
    int g = blockIdx.x >> 3, chunk = blockIdx.x & 7;
    int t = threadIdx.x, l = t & 63, w = t >> 6;
    int k4 = w*8 + (l & 7);
    int d0 = (l >> 3) * 16;
    bool owner = ((l >> 3) == 0);
    int eBase = chunk * CH2;
    int L = meta[g*(NND+1)];

    // load this block's 16 step-0 rows
    for (int idx = t; idx < CH2*DD/4; idx += 256)
        ((float4*)&Vbuf[0][0][0])[idx] =
            ((const float4*)&V0[((size_t)g*EDGEN + eBase)*DD])[idx];
    __syncthreads();

    // ---- shared steps 1..L-1: one W per step, reused across CH2 e-rows ----
    int cur = 0;
    for (int s = 1; s < L; ++s){
        int pn = meta[g*(NND+1) + s];           // path[s-1]
        int ej = edges[pn];
        const float* Wp = EW + (size_t)ej*(DD*DD) + (size_t)d0*DD + 4*k4;
        float4 wr[16];
        #pragma unroll
        for (int d = 0; d < 16; ++d) wr[d] = *(const float4*)&Wp[d*DD];
        float4 us = *(const float4*)&uG[((size_t)g*NND + s)*DD + 4*k4];
        float4 bb = *(const float4*)&EB[(size_t)ej*DD + 4*k4];
        #pragma unroll 4
        for (int p = 0; p < CH2; ++p){
            float ev[16];
            #pragma unroll
            for (int j = 0; j < 4; ++j){
                float4 x = *(const float4*)&Vbuf[cur][p][d0 + 4*j];
                ev[4*j+0]=x.x; ev[4*j+1]=x.y; ev[4*j+2]=x.z; ev[4*j+3]=x.w;
            }
            float s0=0.f, s1=0.f, s2=0.f, s3=0.f;
            #pragma unroll
            for (int d = 0; d < 16; ++d){
                s0 = fmaf(ev[d], wr[d].x, s0);
                s1 = fmaf(ev[d], wr[d].y, s1);
                s2 = fmaf(ev[d], wr[d].z, s2);
                s3 = fmaf(ev[d], wr[d].w, s3);
            }
            #pragma unroll
            for (int m = 8; m <= 32; m <<= 1){
                s0 += __shfl_xor(s0, m); s1 += __shfl_xor(s1, m);
                s2 += __shfl_xor(s2, m); s3 += __shfl_xor(s3, m);
            }
            if (owner){
                float4 r;
                r.x = fmaxf(us.x + s0 + bb.x, 0.f);
                r.y = fmaxf(us.y + s1 + bb.y, 0.f);
                r.z = fmaxf(us.z + s2 + bb.z, 0.f);
                r.w = fmaxf(us.w + s3 + bb.w, 0.f);
                *(float4*)&Vbuf[cur^1][p][4*k4] = r;
            }
        }
        __syncthreads();
        cur ^= 1;
    }

    // ---- final transform (root edge) + score ----
    {
        int rn = meta[g*(NND+1) + L];           // path[L-1] (= 127)
        int er = edges[rn];
        const float* Wp = EW + (size_t)er*(DD*DD) + (size_t)d0*DD + 4*k4;
        float4 wr[16];
        #pragma unroll
        for (int d = 0; d < 16; ++d) wr[d] = *(const float4*)&Wp[d*DD];
        float4 bb = *(const float4*)&EB[(size_t)er*DD + 4*k4];
        float4 sw = *(const float4*)&SEW[4*k4];
        #pragma unroll 4
        for (int p = 0; p < CH2; ++p){
            float ev[16];
            #pragma unroll
            for (int j = 0; j < 4; ++j){
                float4 x = *(const float4*)&Vbuf[cur][p][d0 + 4*j];
                ev[4*j+0]=x.x; ev[4*j+1]=x.y; ev[4*j+2]=x.z; ev[4*j+3]=x.w;
            }
            float s0=0.f, s1=0.f, s2=0.f, s3=0.f;
            #pragma unroll
            for (int d = 0; d < 16; ++d){
                s0 = fmaf(ev[d], wr[d].x, s0);
                s1 = fmaf(ev[d], wr[d].y, s1);
                s2 = fmaf(ev[d], wr[d].z, s2);
                s3 = fmaf(ev[d], wr[d].w, s3);
            }
            #pragma unroll
            for (int m = 8; m <= 32; m <<= 1){
                s0 += __shfl_xor(s0, m); s1 += __shfl_xor(s1, m);
                s2 += __shfl_xor(s2, m); s3 += __shfl_xor(s3, m);
            }
            if (owner){
                float part = (s0 + bb.x) * sw.x + (s1 + bb.y) * sw.y
                           + (s2 + bb.z) * sw.z + (s3 + bb.w) * sw.w;
                part += __shfl_xor(part, 1);
                part += __shfl_xor(part, 2);
                part += __shfl_xor(part, 4);
                if (l == 0) red[p][w] = part;
            }
        }
        __syncthreads();
        if (t < CH2)
            outp[g*DD + eBase + t] = dscore[0] + red[t][0] + red[t][1] + red[t][2] + red[t][3];
    }
}

extern "C" void kernel_launch(void* const* d_in, const int* in_sizes, int n_in,
                              void* d_out, int out_size, void* d_ws, size_t ws_size,
                              hipStream_t stream)
{
    const int*   data   = (const int*)d_in[0];
    /* d_in[1] = types, unused (single data_type) */
    const int*   graphs = (const int*)d_in[2];
    const int*   edges  = (const int*)d_in[3];
    const int*   posArr = (const int*)d_in[4];
    const float* vecs   = (const float*)d_in[5];
    const float* dw     = (const float*)d_in[6];
    const float* db     = (const float*)d_in[7];
    const float* ew     = (const float*)d_in[8];
    const float* eb     = (const float*)d_in[9];
    const float* sew    = (const float*)d_in[10];
    const float* sdw    = (const float*)d_in[11];
    const float* sb     = (const float*)d_in[12];

    char* ws = (char*)d_ws;
    float* base   = (float*)(ws);                               // 64 KB
    float* vposG  = (float*)(ws + 65536);                       // 4 KB
    float* uG     = (float*)(ws + 69632);                       // 512 KB
    float* dscore = (float*)(ws + 593920);                      // 1 f32
    int*   meta   = (int*)  (ws + 594176);                      // 8*129 ints
    float* V0     = (float*)(ws + 598528);                      // 512 KB (k_step0->k_steps)
    float* contribX = V0;                                       // overlay: dead before k_step0
    int*   flagsG = (int*)  (ws + 1122816);                     // 8*128 ints

    float* outp = (float*)d_out;

    k_base <<<NND, 128, 0, stream>>>(data, posArr, vecs, dw, db, sdw, sb,
                                     base, dscore, flagsG);
    k_treeX<<<GG*KSP, 512, 0, stream>>>(graphs, edges, posArr, ew, eb, base,
                                        vposG, uG, meta, contribX, flagsG);
    k_step0<<<EDGEN, 256, 0, stream>>>(ew, eb, vposG, uG, V0);
    k_steps<<<GG*(EDGEN/CH2), 256, 0, stream>>>(edges, ew, eb, sew, uG, V0,
                                                meta, dscore, outp);
}